// Round 9
// baseline (479.044 us; speedup 1.0000x reference)
//
#include <hip/hip_runtime.h>
#include <hip/hip_bf16.h>

using u16 = unsigned short;
typedef short v8s __attribute__((ext_vector_type(8)));
typedef float v4f __attribute__((ext_vector_type(4)));

#define B_ 2
#define T_ 2048
#define C_ 1024
#define NH_ 16
#define HD_ 64
#define FF_ 4096
#define NT (B_*T_)
#define QKVC 3072

__device__ __forceinline__ u16 f2b(float f) {
  union { float f; unsigned int i; } v; v.f = f;
  unsigned int r = (v.i + 0x7FFFu + ((v.i >> 16) & 1u)) >> 16;
  return (u16)r;
}
__device__ __forceinline__ v4f mfma16(v8s a, v8s b, v4f c) {
  return __builtin_amdgcn_mfma_f32_16x16x32_bf16(a, b, c, 0, 0, 0);
}
__device__ __forceinline__ void glds16(const u16* g, u16* l) {
  __builtin_amdgcn_global_load_lds(
      (const __attribute__((address_space(1))) unsigned int*)g,
      (__attribute__((address_space(3))) unsigned int*)l, 16, 0, 0);
}

// ------- weight convert+transpose: W[K,N] fp32 -> Wt[N,K] bf16 -------
__global__ __launch_bounds__(256) void wcvt_kernel(const float* __restrict__ W,
    u16* __restrict__ Wt, int K, int N) {
  __shared__ float t[32][33];
  int tx = threadIdx.x & 31, ty = threadIdx.x >> 5;
  int n0 = blockIdx.x * 32, k0 = blockIdx.y * 32;
#pragma unroll
  for (int j = 0; j < 4; ++j)
    t[ty + j * 8][tx] = W[(size_t)(k0 + ty + j * 8) * N + n0 + tx];
  __syncthreads();
#pragma unroll
  for (int j = 0; j < 4; ++j)
    Wt[(size_t)(n0 + ty + j * 8) * K + k0 + tx] = f2b(t[tx][ty + j * 8]);
}

// ------- LayerNorm: fp32 in -> bf16 out, one block per row (C=1024) -------
__global__ __launch_bounds__(256) void ln_kernel(const float* __restrict__ x,
    const float* __restrict__ w, const float* __restrict__ b, u16* __restrict__ y) {
  int row = blockIdx.x;
  int tid = threadIdx.x;
  const float* xr = x + (size_t)row * C_;
  float4 f4 = *(const float4*)&xr[tid * 4];
  float f[4] = {f4.x, f4.y, f4.z, f4.w};
  float s1 = 0.f, s2 = 0.f;
#pragma unroll
  for (int i = 0; i < 4; ++i) { s1 += f[i]; s2 += f[i] * f[i]; }
#pragma unroll
  for (int off = 32; off > 0; off >>= 1) {
    s1 += __shfl_down(s1, off);
    s2 += __shfl_down(s2, off);
  }
  __shared__ float red[10];
  int lane = tid & 63, wid = tid >> 6;
  if (lane == 0) { red[wid] = s1; red[4 + wid] = s2; }
  __syncthreads();
  if (tid == 0) {
    float a = red[0] + red[1] + red[2] + red[3];
    float q = red[4] + red[5] + red[6] + red[7];
    float mu = a * (1.f / C_);
    float var = q * (1.f / C_) - mu * mu;
    red[8] = mu; red[9] = rsqrtf(var + 1e-5f);
  }
  __syncthreads();
  float mu = red[8], rs = red[9];
  union { uint2 v; u16 s[4]; } st;
#pragma unroll
  for (int i = 0; i < 4; ++i) {
    int c = tid * 4 + i;
    st.s[i] = f2b((f[i] - mu) * rs * w[c] + b[c]);
  }
  *(uint2*)&y[(size_t)row * C_ + tid * 4] = st.v;
}

// ------- GEMM: Y[M,N] = X[M,K] @ Wt[N,K]^T, 128x128 tile, BK=64 ----------
__global__ __launch_bounds__(256) void gemm_bt(const u16* __restrict__ X,
    const u16* __restrict__ Wt, const float* __restrict__ bias,
    const float* __restrict__ resf, u16* __restrict__ Yb, float* __restrict__ Yf,
    float* __restrict__ Yfz1, int M, int N, int lda, int ldb, int kspl, int relu) {
  __shared__ __align__(16) u16 As[2][128 * 32];
  __shared__ __align__(16) u16 Bs[2][128 * 32];
  int tid = threadIdx.x, lane = tid & 63, w = tid >> 6;
  int wm = w >> 1, wn = w & 1, quad = lane >> 4, lcol = lane & 15;
  int m0 = blockIdx.y * 128, n0 = blockIdx.x * 128;
  int koff = blockIdx.z * kspl;
  v4f acc[4][4] = {};
  int sr = lane >> 2, sc = lane & 3;
  const u16* gA = X  + (size_t)(m0 + w * 32 + sr) * lda + koff + sc * 8;
  const u16* gB = Wt + (size_t)(n0 + w * 32 + sr) * ldb + koff + sc * 8;
  u16* lA0 = As[0] + (w * 32) * 32;
  u16* lA1 = As[1] + (w * 32) * 32;
  u16* lB0 = Bs[0] + (w * 32) * 32;
  u16* lB1 = Bs[1] + (w * 32) * 32;
  for (int k0 = 0; k0 < kspl; k0 += 64) {
    __syncthreads();
    glds16(gA + k0,                        lA0);
    glds16(gA + k0 + (size_t)16 * lda,     lA0 + 16 * 32);
    glds16(gA + k0 + 32,                   lA1);
    glds16(gA + k0 + 32 + (size_t)16 * lda, lA1 + 16 * 32);
    glds16(gB + k0,                        lB0);
    glds16(gB + k0 + (size_t)16 * ldb,     lB0 + 16 * 32);
    glds16(gB + k0 + 32,                   lB1);
    glds16(gB + k0 + 32 + (size_t)16 * ldb, lB1 + 16 * 32);
    __syncthreads();
#pragma unroll
    for (int kh = 0; kh < 2; ++kh) {
      v8s a[4], b[4];
#pragma unroll
      for (int i = 0; i < 4; ++i) {
        a[i] = *(v8s*)&As[kh][(wm * 64 + i * 16 + lcol) * 32 + quad * 8];
        b[i] = *(v8s*)&Bs[kh][(wn * 64 + i * 16 + lcol) * 32 + quad * 8];
      }
#pragma unroll
      for (int i = 0; i < 4; ++i)
#pragma unroll
        for (int j = 0; j < 4; ++j)
          acc[i][j] = mfma16(a[i], b[j], acc[i][j]);
    }
  }
  float* yf = blockIdx.z ? Yfz1 : Yf;
#pragma unroll
  for (int i = 0; i < 4; ++i) {
    int mb = m0 + wm * 64 + i * 16 + quad * 4;
#pragma unroll
    for (int j = 0; j < 4; ++j) {
      int n = n0 + wn * 64 + j * 16 + lcol;
#pragma unroll
      for (int r = 0; r < 4; ++r) {
        float v = acc[i][j][r];
        if (bias) v += bias[n];
        if (resf) v += resf[(size_t)(mb + r) * N + n];
        if (relu) v = fmaxf(v, 0.f);
        if (Yb) Yb[(size_t)(mb + r) * N + n] = f2b(v);
        else    yf[(size_t)(mb + r) * N + n] = v;
      }
    }
  }
}

// ------- GEMM variant for small N: 128x64 tile, BK=64 --------------------
__global__ __launch_bounds__(256) void gemm_bt_n64(const u16* __restrict__ X,
    const u16* __restrict__ Wt, const float* __restrict__ bias,
    const float* __restrict__ resf, u16* __restrict__ Yb, float* __restrict__ Yf,
    int M, int N, int K, int relu) {
  __shared__ __align__(16) u16 As[2][128 * 32];
  __shared__ __align__(16) u16 Bs[2][64 * 32];
  int tid = threadIdx.x, lane = tid & 63, w = tid >> 6;
  int wm = w >> 1, wn = w & 1, quad = lane >> 4, lcol = lane & 15;
  int m0 = blockIdx.y * 128, n0 = blockIdx.x * 64;
  v4f acc[4][2] = {};
  int sr = lane >> 2, sc = lane & 3;
  const u16* gA = X  + (size_t)(m0 + w * 32 + sr) * K + sc * 8;
  const u16* gB = Wt + (size_t)(n0 + w * 16 + sr) * K + sc * 8;
  u16* lA0 = As[0] + (w * 32) * 32;
  u16* lA1 = As[1] + (w * 32) * 32;
  u16* lB0 = Bs[0] + (w * 16) * 32;
  u16* lB1 = Bs[1] + (w * 16) * 32;
  for (int k0 = 0; k0 < K; k0 += 64) {
    __syncthreads();
    glds16(gA + k0,                       lA0);
    glds16(gA + k0 + (size_t)16 * K,      lA0 + 16 * 32);
    glds16(gA + k0 + 32,                  lA1);
    glds16(gA + k0 + 32 + (size_t)16 * K, lA1 + 16 * 32);
    glds16(gB + k0,                       lB0);
    glds16(gB + k0 + 32,                  lB1);
    __syncthreads();
#pragma unroll
    for (int kh = 0; kh < 2; ++kh) {
      v8s a[4], b[2];
#pragma unroll
      for (int i = 0; i < 4; ++i)
        a[i] = *(v8s*)&As[kh][(wm * 64 + i * 16 + lcol) * 32 + quad * 8];
#pragma unroll
      for (int j = 0; j < 2; ++j)
        b[j] = *(v8s*)&Bs[kh][(wn * 32 + j * 16 + lcol) * 32 + quad * 8];
#pragma unroll
      for (int i = 0; i < 4; ++i)
#pragma unroll
        for (int j = 0; j < 2; ++j)
          acc[i][j] = mfma16(a[i], b[j], acc[i][j]);
    }
  }
#pragma unroll
  for (int i = 0; i < 4; ++i) {
    int mb = m0 + wm * 64 + i * 16 + quad * 4;
#pragma unroll
    for (int j = 0; j < 2; ++j) {
      int n = n0 + wn * 32 + j * 16 + lcol;
#pragma unroll
      for (int r = 0; r < 4; ++r) {
        float v = acc[i][j][r];
        if (bias) v += bias[n];
        if (resf) v += resf[(size_t)(mb + r) * N + n];
        if (relu) v = fmaxf(v, 0.f);
        if (Yb) Yb[(size_t)(mb + r) * N + n] = f2b(v);
        else    Yf[(size_t)(mb + r) * N + n] = v;
      }
    }
  }
}

// ------- split-K reduce: out = out(p1) + p0 + bias + res ------------------
__global__ __launch_bounds__(256) void add4_kernel(float* __restrict__ out,
    const float* __restrict__ p0, const float* __restrict__ bias,
    const float* __restrict__ res) {
  size_t e0 = ((size_t)blockIdx.x * 256 + threadIdx.x) * 4;
  int col = (int)(e0 & (C_ - 1));
  float4 o = *(float4*)&out[e0];
  float4 p = *(const float4*)&p0[e0];
  float4 r = *(const float4*)&res[e0];
  float4 bb = *(const float4*)&bias[col];
  o.x += p.x + r.x + bb.x;
  o.y += p.y + r.y + bb.y;
  o.z += p.z + r.z + bb.z;
  o.w += p.w + r.w + bb.w;
  *(float4*)&out[e0] = o;
}

// ------- V transpose: QKV v-columns -> VT[bh][d][t] bf16 ------------------
__global__ __launch_bounds__(256) void vt_kernel(const u16* __restrict__ QKV,
    u16* __restrict__ VT) {
  int bh = blockIdx.x, tt = blockIdx.y;
  int b = bh >> 4, h = bh & 15;
  int tid = threadIdx.x;
  __shared__ u16 L[64 * 72];  // L[d][t]
  int r = tid >> 2, g = tid & 3;
  size_t row = ((size_t)(b * T_ + tt * 64 + r)) * QKVC + 2 * C_ + h * HD_;
  union { uint4 v; u16 s[8]; } a0, a1;
  a0.v = *(const uint4*)&QKV[row + g * 8];
  a1.v = *(const uint4*)&QKV[row + 32 + g * 8];
#pragma unroll
  for (int e = 0; e < 8; ++e) L[(g * 8 + e) * 72 + r] = a0.s[e];
#pragma unroll
  for (int e = 0; e < 8; ++e) L[(32 + g * 8 + e) * 72 + r] = a1.s[e];
  __syncthreads();
  size_t orow = ((size_t)(bh * 64 + r)) * T_ + tt * 64;
  *(uint4*)&VT[orow + g * 8]      = *(uint4*)&L[r * 72 + g * 8];
  *(uint4*)&VT[orow + 32 + g * 8] = *(uint4*)&L[r * 72 + 32 + g * 8];
}

// ------- Flash attention (causal): 64-q tile pairs, 16 q per wave ---------
// Grid 32bh x 16 = 512 blocks (2/CU, 2 waves/SIMD). Block handles q-tiles
// (y, 31-y): uniform 33 tile-iters. K-frags ping-pong prefetched.
__global__ __launch_bounds__(256) void attn_kernel(const u16* __restrict__ QKV,
    const u16* __restrict__ VT, u16* __restrict__ Ob) {
  int bh = blockIdx.x, y = blockIdx.y;            // y in [0, 16)
  int b = bh >> 4, h = bh & 15;
  int tid = threadIdx.x, lane = tid & 63, wid = tid >> 6;
  int quad = lane >> 4, lcol = lane & 15;
  __shared__ __align__(16) u16 Ps[4][16 * 72];     // per-wave P[q][kt]
  const float SC = 0.125f * 1.44269504f;           // hd^-0.5 * log2(e)
  const float EB = 8.0f * 1.44269504f;             // fixed exp base (score 8.0)
  const u16* kbase = QKV + (size_t)b * T_ * QKVC + C_ + h * HD_;
  const u16* vbase = VT + (size_t)(bh * 64) * T_;
  u16* psw = Ps[wid];

  auto ldk = [&](v8s (&ak)[4][2], int kb) {
#pragma unroll
    for (int cg = 0; cg < 4; ++cg)
#pragma unroll
      for (int kh = 0; kh < 2; ++kh)
        ak[cg][kh] = *(const v8s*)&kbase[(size_t)(kb * 64 + cg * 16 + lcol) * QKVC + kh * 32 + quad * 8];
  };

#pragma unroll
  for (int pi = 0; pi < 2; ++pi) {
    int qt = pi ? (31 - y) : y;                    // 64-q tile index
    int qg = qt * 64 + wid * 16 + lcol;            // this wave's q rows
    v8s bq[2];
#pragma unroll
    for (int kh = 0; kh < 2; ++kh)
      bq[kh] = *(const v8s*)&QKV[(size_t)(b * T_ + qg) * QKVC + h * HD_ + kh * 32 + quad * 8];
    float l_i = 0.f;
    v4f accO[4] = {};
    int kbmax = qt;                                // diagonal 64-k tile

    auto ctile = [&](v8s (&ak)[4][2], int kb, bool diag) {
      v8s av[4][2];
#pragma unroll
      for (int df = 0; df < 4; ++df)
#pragma unroll
        for (int kh = 0; kh < 2; ++kh)
          av[df][kh] = *(const v8s*)&vbase[(size_t)(df * 16 + lcol) * T_ + kb * 64 + kh * 32 + quad * 8];
      v4f s[4];
#pragma unroll
      for (int cg = 0; cg < 4; ++cg) {
        v4f acc = {};
        acc = mfma16(ak[cg][1], bq[1], acc);
        s[cg] = mfma16(ak[cg][0], bq[0], acc);
      }
      float ps = 0.f;
#pragma unroll
      for (int cg = 0; cg < 4; ++cg) {
        union { u16 s4[4]; unsigned long long ll; } pk;
#pragma unroll
        for (int rg = 0; rg < 4; ++rg) {
          float pv = exp2f(s[cg][rg] * SC - EB);
          if (diag) {
            int kt = kb * 64 + cg * 16 + quad * 4 + rg;
            pv = (kt <= qg) ? pv : 0.f;
          }
          ps += pv;
          pk.s4[rg] = f2b(pv);
        }
        *(unsigned long long*)&psw[lcol * 72 + cg * 16 + quad * 4] = pk.ll;
      }
      ps += __shfl_xor(ps, 16);
      ps += __shfl_xor(ps, 32);
      l_i += ps;
      v8s bp0 = *(v8s*)&psw[lcol * 72 + quad * 8];
      v8s bp1 = *(v8s*)&psw[lcol * 72 + 32 + quad * 8];
#pragma unroll
      for (int df = 0; df < 4; ++df) {
        v4f t = mfma16(av[df][1], bp1, accO[df]);
        accO[df] = mfma16(av[df][0], bp0, t);
      }
    };

    v8s a0k[4][2], a1k[4][2];
    ldk(a0k, 0);
    for (int kb = 0; kb <= kbmax; kb += 2) {
      if (kb + 1 <= kbmax) ldk(a1k, kb + 1);
      ctile(a0k, kb, kb == kbmax);
      if (kb + 1 <= kbmax) {
        if (kb + 2 <= kbmax) ldk(a0k, kb + 2);
        ctile(a1k, kb + 1, (kb + 1) == kbmax);
      }
    }
    float inv = 1.f / l_i;
    size_t orow = ((size_t)(b * T_ + qg)) * C_ + h * HD_;
#pragma unroll
    for (int df = 0; df < 4; ++df) {
      union { u16 s4[4]; unsigned long long ll; } ok;
#pragma unroll
      for (int rg = 0; rg < 4; ++rg) ok.s4[rg] = f2b(accO[df][rg] * inv);
      *(unsigned long long*)&Ob[orow + df * 16 + quad * 4] = ok.ll;
    }
  }
}

extern "C" void kernel_launch(void* const* d_in, const int* in_sizes, int n_in,
                              void* d_out, int out_size, void* d_ws, size_t ws_size,
                              hipStream_t stream) {
  (void)in_sizes; (void)n_in; (void)out_size; (void)ws_size;
  const float* x    = (const float*)d_in[0];
  const float* ln1w = (const float*)d_in[1];
  const float* ln1b = (const float*)d_in[2];
  const float* Wq   = (const float*)d_in[3];
  const float* Wk   = (const float*)d_in[4];
  const float* Wv   = (const float*)d_in[5];
  const float* Wp   = (const float*)d_in[6];
  const float* bp   = (const float*)d_in[7];
  const float* ln2w = (const float*)d_in[8];
  const float* ln2b = (const float*)d_in[9];
  const float* W1   = (const float*)d_in[10];
  const float* b1   = (const float*)d_in[11];
  const float* W2   = (const float*)d_in[12];
  const float* b2   = (const float*)d_in[13];
  float* out = (float*)d_out;
  char* ws = (char*)d_ws;
  const size_t MB = 1024 * 1024;
  u16*   h1    = (u16*)(ws);             // 0..8 MB
  u16*   VT    = (u16*)(ws);             // 0..8 MB, overlays h1
  u16*   QKVb  = (u16*)(ws + 8  * MB);   // 8..32 MB [4096,3072] bf16
  u16*   Ob    = (u16*)(ws + 32 * MB);   // 32..40 MB
  float* xa    = (float*)(ws + 40 * MB); // 40..56 MB fp32
  u16*   h2    = (u16*)(ws);             // overlays VT (dead after attn)
  u16*   f1    = (u16*)(ws + 8 * MB);    // 8..40 MB, overlays QKVb+Ob (dead)
  u16*   Wqkvt = (u16*)(ws + 56 * MB);   // 56..62 MB [3072,1024] bf16
  u16*   Wpt   = (u16*)(ws + 62 * MB);   // 62..64 MB [1024,1024]
  u16*   W1t   = (u16*)(ws + 64 * MB);   // 64..72 MB [4096,1024]
  u16*   W2t   = (u16*)(ws + 72 * MB);   // 72..80 MB [1024,4096]
  float* p0    = (float*)(ws + 56 * MB); // 56..72 MB fp32 partial (weights dead)

  wcvt_kernel<<<dim3(32, 32),  256, 0, stream>>>(Wq, Wqkvt,                1024, 1024);
  wcvt_kernel<<<dim3(32, 32),  256, 0, stream>>>(Wk, Wqkvt + 1024 * 1024,  1024, 1024);
  wcvt_kernel<<<dim3(32, 32),  256, 0, stream>>>(Wv, Wqkvt + 2048 * 1024,  1024, 1024);
  wcvt_kernel<<<dim3(32, 32),  256, 0, stream>>>(Wp, Wpt,                  1024, 1024);
  wcvt_kernel<<<dim3(128, 32), 256, 0, stream>>>(W1, W1t,                  1024, 4096);
  wcvt_kernel<<<dim3(32, 128), 256, 0, stream>>>(W2, W2t,                  4096, 1024);

  ln_kernel<<<NT, 256, 0, stream>>>(x, ln1w, ln1b, h1);
  gemm_bt<<<dim3(QKVC / 128, NT / 128, 1), 256, 0, stream>>>(
      h1, Wqkvt, nullptr, nullptr, QKVb, nullptr, nullptr, NT, QKVC, C_, C_, C_, 0);
  vt_kernel<<<dim3(B_ * NH_, T_ / 64), 256, 0, stream>>>(QKVb, VT);
  attn_kernel<<<dim3(B_ * NH_, T_ / 128), 256, 0, stream>>>(QKVb, VT, Ob);
  gemm_bt_n64<<<dim3(C_ / 64, NT / 128), 256, 0, stream>>>(
      Ob, Wpt, bp, x, nullptr, xa, NT, C_, C_, 0);
  ln_kernel<<<NT, 256, 0, stream>>>(xa, ln2w, ln2b, h2);
  gemm_bt<<<dim3(FF_ / 128, NT / 128, 1), 256, 0, stream>>>(
      h2, W1t, b1, nullptr, f1, nullptr, nullptr, NT, FF_, C_, C_, C_, 1);
  // W2 split-K=2: z=0 -> p0, z=1 -> out; then out = out + p0 + b2 + xa
  gemm_bt<<<dim3(C_ / 128, NT / 128, 2), 256, 0, stream>>>(
      f1, W2t, nullptr, nullptr, nullptr, p0, out, NT, C_, FF_, FF_, FF_ / 2, 0);
  add4_kernel<<<(NT * C_) / (256 * 4), 256, 0, stream>>>(out, p0, b2, xa);
}

// Round 10
// 448.049 us; speedup vs baseline: 1.0692x; 1.0692x over previous
//
#include <hip/hip_runtime.h>
#include <hip/hip_bf16.h>

using u16 = unsigned short;
typedef short v8s __attribute__((ext_vector_type(8)));
typedef float v4f __attribute__((ext_vector_type(4)));

#define B_ 2
#define T_ 2048
#define C_ 1024
#define NH_ 16
#define HD_ 64
#define FF_ 4096
#define NT (B_*T_)
#define QKVC 3072

__device__ __forceinline__ u16 f2b(float f) {
  union { float f; unsigned int i; } v; v.f = f;
  unsigned int r = (v.i + 0x7FFFu + ((v.i >> 16) & 1u)) >> 16;
  return (u16)r;
}
__device__ __forceinline__ float b2f(u16 u) {
  union { unsigned int i; float f; } v; v.i = ((unsigned int)u) << 16; return v.f;
}
__device__ __forceinline__ v4f mfma16(v8s a, v8s b, v4f c) {
  return __builtin_amdgcn_mfma_f32_16x16x32_bf16(a, b, c, 0, 0, 0);
}
__device__ __forceinline__ void glds16(const u16* g, u16* l) {
  __builtin_amdgcn_global_load_lds(
      (const __attribute__((address_space(1))) unsigned int*)g,
      (__attribute__((address_space(3))) unsigned int*)l, 16, 0, 0);
}

// ------- weight convert+transpose: W[K,N] fp32 -> Wt[N,K] bf16 -------
__global__ __launch_bounds__(256) void wcvt_kernel(const float* __restrict__ W,
    u16* __restrict__ Wt, int K, int N) {
  __shared__ float t[32][33];
  int tx = threadIdx.x & 31, ty = threadIdx.x >> 5;
  int n0 = blockIdx.x * 32, k0 = blockIdx.y * 32;
#pragma unroll
  for (int j = 0; j < 4; ++j)
    t[ty + j * 8][tx] = W[(size_t)(k0 + ty + j * 8) * N + n0 + tx];
  __syncthreads();
#pragma unroll
  for (int j = 0; j < 4; ++j)
    Wt[(size_t)(n0 + ty + j * 8) * K + k0 + tx] = f2b(t[tx][ty + j * 8]);
}

// ------- LayerNorm: fp32 in -> bf16 out, one block per row (C=1024) -------
__global__ __launch_bounds__(256) void ln_kernel(const float* __restrict__ x,
    const float* __restrict__ w, const float* __restrict__ b, u16* __restrict__ y) {
  int row = blockIdx.x;
  int tid = threadIdx.x;
  const float* xr = x + (size_t)row * C_;
  float4 f4 = *(const float4*)&xr[tid * 4];
  float f[4] = {f4.x, f4.y, f4.z, f4.w};
  float s1 = 0.f, s2 = 0.f;
#pragma unroll
  for (int i = 0; i < 4; ++i) { s1 += f[i]; s2 += f[i] * f[i]; }
#pragma unroll
  for (int off = 32; off > 0; off >>= 1) {
    s1 += __shfl_down(s1, off);
    s2 += __shfl_down(s2, off);
  }
  __shared__ float red[10];
  int lane = tid & 63, wid = tid >> 6;
  if (lane == 0) { red[wid] = s1; red[4 + wid] = s2; }
  __syncthreads();
  if (tid == 0) {
    float a = red[0] + red[1] + red[2] + red[3];
    float q = red[4] + red[5] + red[6] + red[7];
    float mu = a * (1.f / C_);
    float var = q * (1.f / C_) - mu * mu;
    red[8] = mu; red[9] = rsqrtf(var + 1e-5f);
  }
  __syncthreads();
  float mu = red[8], rs = red[9];
  union { uint2 v; u16 s[4]; } st;
#pragma unroll
  for (int i = 0; i < 4; ++i) {
    int c = tid * 4 + i;
    st.s[i] = f2b((f[i] - mu) * rs * w[c] + b[c]);
  }
  *(uint2*)&y[(size_t)row * C_ + tid * 4] = st.v;
}

// ------- GEMM: Y[M,N] = X[M,K] @ Wt[N,K]^T, 128x128 tile, BK=64 ----------
__global__ __launch_bounds__(256) void gemm_bt(const u16* __restrict__ X,
    const u16* __restrict__ Wt, const float* __restrict__ bias,
    const float* __restrict__ resf, u16* __restrict__ Yb, float* __restrict__ Yf,
    float* __restrict__ Yfz1, int M, int N, int lda, int ldb, int kspl, int relu) {
  __shared__ __align__(16) u16 As[2][128 * 32];
  __shared__ __align__(16) u16 Bs[2][128 * 32];
  int tid = threadIdx.x, lane = tid & 63, w = tid >> 6;
  int wm = w >> 1, wn = w & 1, quad = lane >> 4, lcol = lane & 15;
  int m0 = blockIdx.y * 128, n0 = blockIdx.x * 128;
  int koff = blockIdx.z * kspl;
  v4f acc[4][4] = {};
  int sr = lane >> 2, sc = lane & 3;
  const u16* gA = X  + (size_t)(m0 + w * 32 + sr) * lda + koff + sc * 8;
  const u16* gB = Wt + (size_t)(n0 + w * 32 + sr) * ldb + koff + sc * 8;
  u16* lA0 = As[0] + (w * 32) * 32;
  u16* lA1 = As[1] + (w * 32) * 32;
  u16* lB0 = Bs[0] + (w * 32) * 32;
  u16* lB1 = Bs[1] + (w * 32) * 32;
  for (int k0 = 0; k0 < kspl; k0 += 64) {
    __syncthreads();
    glds16(gA + k0,                        lA0);
    glds16(gA + k0 + (size_t)16 * lda,     lA0 + 16 * 32);
    glds16(gA + k0 + 32,                   lA1);
    glds16(gA + k0 + 32 + (size_t)16 * lda, lA1 + 16 * 32);
    glds16(gB + k0,                        lB0);
    glds16(gB + k0 + (size_t)16 * ldb,     lB0 + 16 * 32);
    glds16(gB + k0 + 32,                   lB1);
    glds16(gB + k0 + 32 + (size_t)16 * ldb, lB1 + 16 * 32);
    __syncthreads();
#pragma unroll
    for (int kh = 0; kh < 2; ++kh) {
      v8s a[4], b[4];
#pragma unroll
      for (int i = 0; i < 4; ++i) {
        a[i] = *(v8s*)&As[kh][(wm * 64 + i * 16 + lcol) * 32 + quad * 8];
        b[i] = *(v8s*)&Bs[kh][(wn * 64 + i * 16 + lcol) * 32 + quad * 8];
      }
#pragma unroll
      for (int i = 0; i < 4; ++i)
#pragma unroll
        for (int j = 0; j < 4; ++j)
          acc[i][j] = mfma16(a[i], b[j], acc[i][j]);
    }
  }
  float* yf = blockIdx.z ? Yfz1 : Yf;
#pragma unroll
  for (int i = 0; i < 4; ++i) {
    int mb = m0 + wm * 64 + i * 16 + quad * 4;
#pragma unroll
    for (int j = 0; j < 4; ++j) {
      int n = n0 + wn * 64 + j * 16 + lcol;
#pragma unroll
      for (int r = 0; r < 4; ++r) {
        float v = acc[i][j][r];
        if (bias) v += bias[n];
        if (resf) v += resf[(size_t)(mb + r) * N + n];
        if (relu) v = fmaxf(v, 0.f);
        if (Yb) Yb[(size_t)(mb + r) * N + n] = f2b(v);
        else    yf[(size_t)(mb + r) * N + n] = v;
      }
    }
  }
}

// ------- GEMM variant for small N: 128x64 tile, BK=64 --------------------
__global__ __launch_bounds__(256) void gemm_bt_n64(const u16* __restrict__ X,
    const u16* __restrict__ Wt, const float* __restrict__ bias,
    const float* __restrict__ resf, u16* __restrict__ Yb, float* __restrict__ Yf,
    int M, int N, int K, int relu) {
  __shared__ __align__(16) u16 As[2][128 * 32];
  __shared__ __align__(16) u16 Bs[2][64 * 32];
  int tid = threadIdx.x, lane = tid & 63, w = tid >> 6;
  int wm = w >> 1, wn = w & 1, quad = lane >> 4, lcol = lane & 15;
  int m0 = blockIdx.y * 128, n0 = blockIdx.x * 64;
  v4f acc[4][2] = {};
  int sr = lane >> 2, sc = lane & 3;
  const u16* gA = X  + (size_t)(m0 + w * 32 + sr) * K + sc * 8;
  const u16* gB = Wt + (size_t)(n0 + w * 16 + sr) * K + sc * 8;
  u16* lA0 = As[0] + (w * 32) * 32;
  u16* lA1 = As[1] + (w * 32) * 32;
  u16* lB0 = Bs[0] + (w * 16) * 32;
  u16* lB1 = Bs[1] + (w * 16) * 32;
  for (int k0 = 0; k0 < K; k0 += 64) {
    __syncthreads();
    glds16(gA + k0,                       lA0);
    glds16(gA + k0 + (size_t)16 * K,      lA0 + 16 * 32);
    glds16(gA + k0 + 32,                  lA1);
    glds16(gA + k0 + 32 + (size_t)16 * K, lA1 + 16 * 32);
    glds16(gB + k0,                       lB0);
    glds16(gB + k0 + 32,                  lB1);
    __syncthreads();
#pragma unroll
    for (int kh = 0; kh < 2; ++kh) {
      v8s a[4], b[2];
#pragma unroll
      for (int i = 0; i < 4; ++i)
        a[i] = *(v8s*)&As[kh][(wm * 64 + i * 16 + lcol) * 32 + quad * 8];
#pragma unroll
      for (int j = 0; j < 2; ++j)
        b[j] = *(v8s*)&Bs[kh][(wn * 32 + j * 16 + lcol) * 32 + quad * 8];
#pragma unroll
      for (int i = 0; i < 4; ++i)
#pragma unroll
        for (int j = 0; j < 2; ++j)
          acc[i][j] = mfma16(a[i], b[j], acc[i][j]);
    }
  }
#pragma unroll
  for (int i = 0; i < 4; ++i) {
    int mb = m0 + wm * 64 + i * 16 + quad * 4;
#pragma unroll
    for (int j = 0; j < 2; ++j) {
      int n = n0 + wn * 32 + j * 16 + lcol;
#pragma unroll
      for (int r = 0; r < 4; ++r) {
        float v = acc[i][j][r];
        if (bias) v += bias[n];
        if (resf) v += resf[(size_t)(mb + r) * N + n];
        if (relu) v = fmaxf(v, 0.f);
        if (Yb) Yb[(size_t)(mb + r) * N + n] = f2b(v);
        else    Yf[(size_t)(mb + r) * N + n] = v;
      }
    }
  }
}

// ------- split-K reduce: out = out(p1) + p0 + bias + res ------------------
__global__ __launch_bounds__(256) void add4_kernel(float* __restrict__ out,
    const float* __restrict__ p0, const float* __restrict__ bias,
    const float* __restrict__ res) {
  size_t e0 = ((size_t)blockIdx.x * 256 + threadIdx.x) * 4;
  int col = (int)(e0 & (C_ - 1));
  float4 o = *(float4*)&out[e0];
  float4 p = *(const float4*)&p0[e0];
  float4 r = *(const float4*)&res[e0];
  float4 bb = *(const float4*)&bias[col];
  o.x += p.x + r.x + bb.x;
  o.y += p.y + r.y + bb.y;
  o.z += p.z + r.z + bb.z;
  o.w += p.w + r.w + bb.w;
  *(float4*)&out[e0] = o;
}

// ------- V transpose: QKV v-columns -> VT[bh][d][t] bf16 ------------------
__global__ __launch_bounds__(256) void vt_kernel(const u16* __restrict__ QKV,
    u16* __restrict__ VT) {
  int bh = blockIdx.x, tt = blockIdx.y;
  int b = bh >> 4, h = bh & 15;
  int tid = threadIdx.x;
  __shared__ u16 L[64 * 72];  // L[d][t]
  int r = tid >> 2, g = tid & 3;
  size_t row = ((size_t)(b * T_ + tt * 64 + r)) * QKVC + 2 * C_ + h * HD_;
  union { uint4 v; u16 s[8]; } a0, a1;
  a0.v = *(const uint4*)&QKV[row + g * 8];
  a1.v = *(const uint4*)&QKV[row + 32 + g * 8];
#pragma unroll
  for (int e = 0; e < 8; ++e) L[(g * 8 + e) * 72 + r] = a0.s[e];
#pragma unroll
  for (int e = 0; e < 8; ++e) L[(32 + g * 8 + e) * 72 + r] = a1.s[e];
  __syncthreads();
  size_t orow = ((size_t)(bh * 64 + r)) * T_ + tt * 64;
  *(uint4*)&VT[orow + g * 8]      = *(uint4*)&L[r * 72 + g * 8];
  *(uint4*)&VT[orow + 32 + g * 8] = *(uint4*)&L[r * 72 + 32 + g * 8];
}

// ------- Flash attention (causal): R8 shape + KV-split (z=2) --------------
// Block = (bh, y, z): q-tiles (y, 15-y) of 128q, 32q/wave (2 j-strips);
// split z covers half the k-tiles. Partials: O_s = A_s/l_s (bf16) + l_s.
__global__ __launch_bounds__(256) void attn_kernel(const u16* __restrict__ QKV,
    const u16* __restrict__ VT, u16* __restrict__ Opart, float* __restrict__ lpart) {
  int bh = blockIdx.x, y = blockIdx.y, z = blockIdx.z;
  int b = bh >> 4, h = bh & 15;
  int tid = threadIdx.x, lane = tid & 63, wid = tid >> 6;
  int quad = lane >> 4, lcol = lane & 15;
  __shared__ __align__(16) u16 Ps[4][32 * 72];     // per-wave P[q][kt]
  const float SC = 0.125f * 1.44269504f;           // hd^-0.5 * log2(e)
  const float EB = 8.0f * 1.44269504f;             // fixed exp base (score 8.0)
  const u16* kbase = QKV + (size_t)b * T_ * QKVC + C_ + h * HD_;
  const u16* vbase = VT + (size_t)(bh * 64) * T_;
  u16* psw = Ps[wid];
  u16* Os = Opart + (size_t)z * NT * C_;
  float* ls = lpart + (size_t)z * 32 * T_;

  auto ldk = [&](v8s (&ak)[4][2], int kb) {
#pragma unroll
    for (int cg = 0; cg < 4; ++cg)
#pragma unroll
      for (int kh = 0; kh < 2; ++kh)
        ak[cg][kh] = *(const v8s*)&kbase[(size_t)(kb * 64 + cg * 16 + lcol) * QKVC + kh * 32 + quad * 8];
  };

#pragma unroll
  for (int pi = 0; pi < 2; ++pi) {
    int qt = pi ? (15 - y) : y;
    int qg[2];
    v8s bq[2][2];
#pragma unroll
    for (int j = 0; j < 2; ++j) {
      qg[j] = qt * 128 + wid * 32 + j * 16 + lcol;
#pragma unroll
      for (int kh = 0; kh < 2; ++kh)
        bq[j][kh] = *(const v8s*)&QKV[(size_t)(b * T_ + qg[j]) * QKVC + h * HD_ + kh * 32 + quad * 8];
    }
    float l_i[2] = {0.f, 0.f};
    v4f accO[4][2] = {};
    int kbmax = 2 * qt + (wid >> 1);               // wave-uniform diagonal tile
    int mid = (kbmax + 2) >> 1;                    // split point (split0 gets +1)
    int lo = z ? mid : 0;
    int hi = z ? kbmax : (mid - 1);

    auto ctile = [&](v8s (&ak)[4][2], int kb, bool diag) {
      v8s av[4][2];
#pragma unroll
      for (int df = 0; df < 4; ++df)
#pragma unroll
        for (int kh = 0; kh < 2; ++kh)
          av[df][kh] = *(const v8s*)&vbase[(size_t)(df * 16 + lcol) * T_ + kb * 64 + kh * 32 + quad * 8];
#pragma unroll
      for (int j = 0; j < 2; ++j) {
        v4f s[4];
#pragma unroll
        for (int cg = 0; cg < 4; ++cg) {
          v4f acc = {};
          acc = mfma16(ak[cg][1], bq[j][1], acc);
          s[cg] = mfma16(ak[cg][0], bq[j][0], acc);
        }
        float ps = 0.f;
#pragma unroll
        for (int cg = 0; cg < 4; ++cg) {
          union { u16 s4[4]; unsigned long long ll; } pk;
#pragma unroll
          for (int rg = 0; rg < 4; ++rg) {
            float pv = exp2f(s[cg][rg] * SC - EB);
            if (diag) {
              int kt = kb * 64 + cg * 16 + quad * 4 + rg;
              pv = (kt <= qg[j]) ? pv : 0.f;
            }
            ps += pv;
            pk.s4[rg] = f2b(pv);
          }
          *(unsigned long long*)&psw[(j * 16 + lcol) * 72 + cg * 16 + quad * 4] = pk.ll;
        }
        ps += __shfl_xor(ps, 16);
        ps += __shfl_xor(ps, 32);
        l_i[j] += ps;
        v8s bp0 = *(v8s*)&psw[(j * 16 + lcol) * 72 + quad * 8];
        v8s bp1 = *(v8s*)&psw[(j * 16 + lcol) * 72 + 32 + quad * 8];
#pragma unroll
        for (int df = 0; df < 4; ++df) {
          v4f t = mfma16(av[df][1], bp1, accO[df][j]);
          accO[df][j] = mfma16(av[df][0], bp0, t);
        }
      }
    };

    if (lo <= hi) {
      v8s a0k[4][2], a1k[4][2];
      ldk(a0k, lo);
      for (int kb = lo; kb <= hi; kb += 2) {
        if (kb + 1 <= hi) ldk(a1k, kb + 1);
        ctile(a0k, kb, kb == kbmax);
        if (kb + 1 <= hi) {
          if (kb + 2 <= hi) ldk(a0k, kb + 2);
          ctile(a1k, kb + 1, (kb + 1) == kbmax);
        }
      }
    }
#pragma unroll
    for (int j = 0; j < 2; ++j) {
      float inv = (l_i[j] > 0.f) ? (1.f / l_i[j]) : 0.f;
      size_t orow = ((size_t)(b * T_ + qg[j])) * C_ + h * HD_;
      if (quad == 0) ls[bh * T_ + qg[j]] = l_i[j];
#pragma unroll
      for (int df = 0; df < 4; ++df) {
        union { u16 s4[4]; unsigned long long ll; } ok;
#pragma unroll
        for (int rg = 0; rg < 4; ++rg) ok.s4[rg] = f2b(accO[df][j][rg] * inv);
        *(unsigned long long*)&Os[orow + df * 16 + quad * 4] = ok.ll;
      }
    }
  }
}

// ------- attention split combine: Ob = (O0*l0 + O1*l1)/(l0+l1) ------------
__global__ __launch_bounds__(256) void ared_kernel(const u16* __restrict__ Opart,
    const float* __restrict__ lpart, u16* __restrict__ Ob) {
  size_t e0 = ((size_t)blockIdx.x * 256 + threadIdx.x) * 4;
  int tb = (int)(e0 >> 10);                 // b*T + t
  int col = (int)(e0 & (C_ - 1));
  int bq = tb >> 11, t = tb & (T_ - 1);
  int h = col >> 6;
  int lidx = (bq * 16 + h) * T_ + t;
  float l0 = lpart[lidx], l1 = lpart[32 * T_ + lidx];
  float inv = 1.f / (l0 + l1);
  float w0 = l0 * inv, w1 = l1 * inv;
  union { uint2 v; u16 s[4]; } a, b, o;
  a.v = *(const uint2*)&Opart[e0];
  b.v = *(const uint2*)&Opart[(size_t)NT * C_ + e0];
#pragma unroll
  for (int i = 0; i < 4; ++i)
    o.s[i] = f2b(b2f(a.s[i]) * w0 + b2f(b.s[i]) * w1);
  *(uint2*)&Ob[e0] = o.v;
}

extern "C" void kernel_launch(void* const* d_in, const int* in_sizes, int n_in,
                              void* d_out, int out_size, void* d_ws, size_t ws_size,
                              hipStream_t stream) {
  (void)in_sizes; (void)n_in; (void)out_size; (void)ws_size;
  const float* x    = (const float*)d_in[0];
  const float* ln1w = (const float*)d_in[1];
  const float* ln1b = (const float*)d_in[2];
  const float* Wq   = (const float*)d_in[3];
  const float* Wk   = (const float*)d_in[4];
  const float* Wv   = (const float*)d_in[5];
  const float* Wp   = (const float*)d_in[6];
  const float* bp   = (const float*)d_in[7];
  const float* ln2w = (const float*)d_in[8];
  const float* ln2b = (const float*)d_in[9];
  const float* W1   = (const float*)d_in[10];
  const float* b1   = (const float*)d_in[11];
  const float* W2   = (const float*)d_in[12];
  const float* b2   = (const float*)d_in[13];
  float* out = (float*)d_out;
  char* ws = (char*)d_ws;
  const size_t MB = 1024 * 1024;
  u16*   h1    = (u16*)(ws);             // 0..8 MB
  u16*   VT    = (u16*)(ws);             // 0..8 MB, overlays h1
  u16*   QKVb  = (u16*)(ws + 8  * MB);   // 8..32 MB [4096,3072] bf16
  u16*   Ob    = (u16*)(ws + 32 * MB);   // 32..40 MB
  float* xa    = (float*)(ws + 40 * MB); // 40..56 MB fp32 (after attn reduce)
  u16*   Opart = (u16*)(ws + 40 * MB);   // 40..56 MB: 2x bf16 [4096,1024] partials
  u16*   h2    = (u16*)(ws);             // overlays VT (dead after attn)
  u16*   f1    = (u16*)(ws + 8 * MB);    // 8..40 MB, overlays QKVb+Ob (dead)
  u16*   Wqkvt = (u16*)(ws + 56 * MB);   // 56..62 MB [3072,1024] bf16
  float* lpart = (float*)(ws + 56 * MB); // 56..56.5 MB, overlays dead Wqkvt
  u16*   Wpt   = (u16*)(ws + 62 * MB);   // 62..64 MB [1024,1024]
  u16*   W1t   = (u16*)(ws + 64 * MB);   // 64..72 MB [4096,1024]
  u16*   W2t   = (u16*)(ws + 72 * MB);   // 72..80 MB [1024,4096]
  float* p0    = (float*)(ws + 56 * MB); // 56..72 MB fp32 partial (W2 stage)

  wcvt_kernel<<<dim3(32, 32),  256, 0, stream>>>(Wq, Wqkvt,                1024, 1024);
  wcvt_kernel<<<dim3(32, 32),  256, 0, stream>>>(Wk, Wqkvt + 1024 * 1024,  1024, 1024);
  wcvt_kernel<<<dim3(32, 32),  256, 0, stream>>>(Wv, Wqkvt + 2048 * 1024,  1024, 1024);
  wcvt_kernel<<<dim3(32, 32),  256, 0, stream>>>(Wp, Wpt,                  1024, 1024);
  wcvt_kernel<<<dim3(128, 32), 256, 0, stream>>>(W1, W1t,                  1024, 4096);
  wcvt_kernel<<<dim3(32, 128), 256, 0, stream>>>(W2, W2t,                  4096, 1024);

  ln_kernel<<<NT, 256, 0, stream>>>(x, ln1w, ln1b, h1);
  gemm_bt<<<dim3(QKVC / 128, NT / 128, 1), 256, 0, stream>>>(
      h1, Wqkvt, nullptr, nullptr, QKVb, nullptr, nullptr, NT, QKVC, C_, C_, C_, 0);
  vt_kernel<<<dim3(B_ * NH_, T_ / 64), 256, 0, stream>>>(QKVb, VT);
  attn_kernel<<<dim3(B_ * NH_, T_ / 256, 2), 256, 0, stream>>>(QKVb, VT, Opart, lpart);
  ared_kernel<<<(NT * C_) / (256 * 4), 256, 0, stream>>>(Opart, lpart, Ob);
  gemm_bt_n64<<<dim3(C_ / 64, NT / 128), 256, 0, stream>>>(
      Ob, Wpt, bp, x, nullptr, xa, NT, C_, C_, 0);
  ln_kernel<<<NT, 256, 0, stream>>>(xa, ln2w, ln2b, h2);
  gemm_bt<<<dim3(FF_ / 128, NT / 128, 1), 256, 0, stream>>>(
      h2, W1t, b1, nullptr, f1, nullptr, nullptr, NT, FF_, C_, C_, C_, 1);
  // W2 split-K=2: z=0 -> p0, z=1 -> out; then out = out + p0 + b2 + xa
  gemm_bt<<<dim3(C_ / 128, NT / 128, 2), 256, 0, stream>>>(
      f1, W2t, nullptr, nullptr, nullptr, p0, out, NT, C_, FF_, FF_, FF_ / 2, 0);
  add4_kernel<<<(NT * C_) / (256 * 4), 256, 0, stream>>>(out, p0, b2, xa);
}

// Round 11
// 430.220 us; speedup vs baseline: 1.1135x; 1.0414x over previous
//
#include <hip/hip_runtime.h>
#include <hip/hip_bf16.h>

using u16 = unsigned short;
typedef short v8s __attribute__((ext_vector_type(8)));
typedef float v4f __attribute__((ext_vector_type(4)));

#define B_ 2
#define T_ 2048
#define C_ 1024
#define NH_ 16
#define HD_ 64
#define FF_ 4096
#define NT (B_*T_)
#define QKVC 3072

__device__ __forceinline__ u16 f2b(float f) {
  union { float f; unsigned int i; } v; v.f = f;
  unsigned int r = (v.i + 0x7FFFu + ((v.i >> 16) & 1u)) >> 16;
  return (u16)r;
}
__device__ __forceinline__ u16 f2bt(float f) {   // truncating bf16 (1 op)
  union { float f; unsigned int i; } v; v.f = f;
  return (u16)(v.i >> 16);
}
__device__ __forceinline__ float b2f(u16 u) {
  union { unsigned int i; float f; } v; v.i = ((unsigned int)u) << 16; return v.f;
}
__device__ __forceinline__ v4f mfma16(v8s a, v8s b, v4f c) {
  return __builtin_amdgcn_mfma_f32_16x16x32_bf16(a, b, c, 0, 0, 0);
}
__device__ __forceinline__ void glds16(const u16* g, u16* l) {
  __builtin_amdgcn_global_load_lds(
      (const __attribute__((address_space(1))) unsigned int*)g,
      (__attribute__((address_space(3))) unsigned int*)l, 16, 0, 0);
}

// ------- weight convert+transpose: W[K,N] fp32 -> Wt[N,K] bf16 -------
__global__ __launch_bounds__(256) void wcvt_kernel(const float* __restrict__ W,
    u16* __restrict__ Wt, int K, int N) {
  __shared__ float t[32][33];
  int tx = threadIdx.x & 31, ty = threadIdx.x >> 5;
  int n0 = blockIdx.x * 32, k0 = blockIdx.y * 32;
#pragma unroll
  for (int j = 0; j < 4; ++j)
    t[ty + j * 8][tx] = W[(size_t)(k0 + ty + j * 8) * N + n0 + tx];
  __syncthreads();
#pragma unroll
  for (int j = 0; j < 4; ++j)
    Wt[(size_t)(n0 + ty + j * 8) * K + k0 + tx] = f2b(t[tx][ty + j * 8]);
}

// ------- LayerNorm: fp32 in -> bf16 out, one block per row (C=1024) -------
__global__ __launch_bounds__(256) void ln_kernel(const float* __restrict__ x,
    const float* __restrict__ w, const float* __restrict__ b, u16* __restrict__ y) {
  int row = blockIdx.x;
  int tid = threadIdx.x;
  const float* xr = x + (size_t)row * C_;
  float4 f4 = *(const float4*)&xr[tid * 4];
  float f[4] = {f4.x, f4.y, f4.z, f4.w};
  float s1 = 0.f, s2 = 0.f;
#pragma unroll
  for (int i = 0; i < 4; ++i) { s1 += f[i]; s2 += f[i] * f[i]; }
#pragma unroll
  for (int off = 32; off > 0; off >>= 1) {
    s1 += __shfl_down(s1, off);
    s2 += __shfl_down(s2, off);
  }
  __shared__ float red[10];
  int lane = tid & 63, wid = tid >> 6;
  if (lane == 0) { red[wid] = s1; red[4 + wid] = s2; }
  __syncthreads();
  if (tid == 0) {
    float a = red[0] + red[1] + red[2] + red[3];
    float q = red[4] + red[5] + red[6] + red[7];
    float mu = a * (1.f / C_);
    float var = q * (1.f / C_) - mu * mu;
    red[8] = mu; red[9] = rsqrtf(var + 1e-5f);
  }
  __syncthreads();
  float mu = red[8], rs = red[9];
  union { uint2 v; u16 s[4]; } st;
#pragma unroll
  for (int i = 0; i < 4; ++i) {
    int c = tid * 4 + i;
    st.s[i] = f2b((f[i] - mu) * rs * w[c] + b[c]);
  }
  *(uint2*)&y[(size_t)row * C_ + tid * 4] = st.v;
}

// ------- GEMM: Y[M,N] = X[M,K] @ Wt[N,K]^T, 128x128 tile, BK=64 ----------
__global__ __launch_bounds__(256) void gemm_bt(const u16* __restrict__ X,
    const u16* __restrict__ Wt, const float* __restrict__ bias,
    const float* __restrict__ resf, u16* __restrict__ Yb, float* __restrict__ Yf,
    float* __restrict__ Yfz1, int M, int N, int lda, int ldb, int kspl, int relu) {
  __shared__ __align__(16) u16 As[2][128 * 32];
  __shared__ __align__(16) u16 Bs[2][128 * 32];
  int tid = threadIdx.x, lane = tid & 63, w = tid >> 6;
  int wm = w >> 1, wn = w & 1, quad = lane >> 4, lcol = lane & 15;
  int m0 = blockIdx.y * 128, n0 = blockIdx.x * 128;
  int koff = blockIdx.z * kspl;
  v4f acc[4][4] = {};
  int sr = lane >> 2, sc = lane & 3;
  const u16* gA = X  + (size_t)(m0 + w * 32 + sr) * lda + koff + sc * 8;
  const u16* gB = Wt + (size_t)(n0 + w * 32 + sr) * ldb + koff + sc * 8;
  u16* lA0 = As[0] + (w * 32) * 32;
  u16* lA1 = As[1] + (w * 32) * 32;
  u16* lB0 = Bs[0] + (w * 32) * 32;
  u16* lB1 = Bs[1] + (w * 32) * 32;
  for (int k0 = 0; k0 < kspl; k0 += 64) {
    __syncthreads();
    glds16(gA + k0,                        lA0);
    glds16(gA + k0 + (size_t)16 * lda,     lA0 + 16 * 32);
    glds16(gA + k0 + 32,                   lA1);
    glds16(gA + k0 + 32 + (size_t)16 * lda, lA1 + 16 * 32);
    glds16(gB + k0,                        lB0);
    glds16(gB + k0 + (size_t)16 * ldb,     lB0 + 16 * 32);
    glds16(gB + k0 + 32,                   lB1);
    glds16(gB + k0 + 32 + (size_t)16 * ldb, lB1 + 16 * 32);
    __syncthreads();
#pragma unroll
    for (int kh = 0; kh < 2; ++kh) {
      v8s a[4], b[4];
#pragma unroll
      for (int i = 0; i < 4; ++i) {
        a[i] = *(v8s*)&As[kh][(wm * 64 + i * 16 + lcol) * 32 + quad * 8];
        b[i] = *(v8s*)&Bs[kh][(wn * 64 + i * 16 + lcol) * 32 + quad * 8];
      }
#pragma unroll
      for (int i = 0; i < 4; ++i)
#pragma unroll
        for (int j = 0; j < 4; ++j)
          acc[i][j] = mfma16(a[i], b[j], acc[i][j]);
    }
  }
  float* yf = blockIdx.z ? Yfz1 : Yf;
#pragma unroll
  for (int i = 0; i < 4; ++i) {
    int mb = m0 + wm * 64 + i * 16 + quad * 4;
#pragma unroll
    for (int j = 0; j < 4; ++j) {
      int n = n0 + wn * 64 + j * 16 + lcol;
#pragma unroll
      for (int r = 0; r < 4; ++r) {
        float v = acc[i][j][r];
        if (bias) v += bias[n];
        if (resf) v += resf[(size_t)(mb + r) * N + n];
        if (relu) v = fmaxf(v, 0.f);
        if (Yb) Yb[(size_t)(mb + r) * N + n] = f2b(v);
        else    yf[(size_t)(mb + r) * N + n] = v;
      }
    }
  }
}

// ------- GEMM variant for small N: 128x64 tile, BK=64 --------------------
__global__ __launch_bounds__(256) void gemm_bt_n64(const u16* __restrict__ X,
    const u16* __restrict__ Wt, const float* __restrict__ bias,
    const float* __restrict__ resf, u16* __restrict__ Yb, float* __restrict__ Yf,
    int M, int N, int K, int relu) {
  __shared__ __align__(16) u16 As[2][128 * 32];
  __shared__ __align__(16) u16 Bs[2][64 * 32];
  int tid = threadIdx.x, lane = tid & 63, w = tid >> 6;
  int wm = w >> 1, wn = w & 1, quad = lane >> 4, lcol = lane & 15;
  int m0 = blockIdx.y * 128, n0 = blockIdx.x * 64;
  v4f acc[4][2] = {};
  int sr = lane >> 2, sc = lane & 3;
  const u16* gA = X  + (size_t)(m0 + w * 32 + sr) * K + sc * 8;
  const u16* gB = Wt + (size_t)(n0 + w * 16 + sr) * K + sc * 8;
  u16* lA0 = As[0] + (w * 32) * 32;
  u16* lA1 = As[1] + (w * 32) * 32;
  u16* lB0 = Bs[0] + (w * 16) * 32;
  u16* lB1 = Bs[1] + (w * 16) * 32;
  for (int k0 = 0; k0 < K; k0 += 64) {
    __syncthreads();
    glds16(gA + k0,                       lA0);
    glds16(gA + k0 + (size_t)16 * K,      lA0 + 16 * 32);
    glds16(gA + k0 + 32,                  lA1);
    glds16(gA + k0 + 32 + (size_t)16 * K, lA1 + 16 * 32);
    glds16(gB + k0,                       lB0);
    glds16(gB + k0 + 32,                  lB1);
    __syncthreads();
#pragma unroll
    for (int kh = 0; kh < 2; ++kh) {
      v8s a[4], b[2];
#pragma unroll
      for (int i = 0; i < 4; ++i)
        a[i] = *(v8s*)&As[kh][(wm * 64 + i * 16 + lcol) * 32 + quad * 8];
#pragma unroll
      for (int j = 0; j < 2; ++j)
        b[j] = *(v8s*)&Bs[kh][(wn * 32 + j * 16 + lcol) * 32 + quad * 8];
#pragma unroll
      for (int i = 0; i < 4; ++i)
#pragma unroll
        for (int j = 0; j < 2; ++j)
          acc[i][j] = mfma16(a[i], b[j], acc[i][j]);
    }
  }
#pragma unroll
  for (int i = 0; i < 4; ++i) {
    int mb = m0 + wm * 64 + i * 16 + quad * 4;
#pragma unroll
    for (int j = 0; j < 2; ++j) {
      int n = n0 + wn * 32 + j * 16 + lcol;
#pragma unroll
      for (int r = 0; r < 4; ++r) {
        float v = acc[i][j][r];
        if (bias) v += bias[n];
        if (resf) v += resf[(size_t)(mb + r) * N + n];
        if (relu) v = fmaxf(v, 0.f);
        if (Yb) Yb[(size_t)(mb + r) * N + n] = f2b(v);
        else    Yf[(size_t)(mb + r) * N + n] = v;
      }
    }
  }
}

// ------- split-K reduce: out = out(p1) + p0 + bias + res ------------------
__global__ __launch_bounds__(256) void add4_kernel(float* __restrict__ out,
    const float* __restrict__ p0, const float* __restrict__ bias,
    const float* __restrict__ res) {
  size_t e0 = ((size_t)blockIdx.x * 256 + threadIdx.x) * 4;
  int col = (int)(e0 & (C_ - 1));
  float4 o = *(float4*)&out[e0];
  float4 p = *(const float4*)&p0[e0];
  float4 r = *(const float4*)&res[e0];
  float4 bb = *(const float4*)&bias[col];
  o.x += p.x + r.x + bb.x;
  o.y += p.y + r.y + bb.y;
  o.z += p.z + r.z + bb.z;
  o.w += p.w + r.w + bb.w;
  *(float4*)&out[e0] = o;
}

// ------- V transpose: QKV v-columns -> VT[bh][d][t] bf16 ------------------
__global__ __launch_bounds__(256) void vt_kernel(const u16* __restrict__ QKV,
    u16* __restrict__ VT) {
  int bh = blockIdx.x, tt = blockIdx.y;
  int b = bh >> 4, h = bh & 15;
  int tid = threadIdx.x;
  __shared__ u16 L[64 * 72];  // L[d][t]
  int r = tid >> 2, g = tid & 3;
  size_t row = ((size_t)(b * T_ + tt * 64 + r)) * QKVC + 2 * C_ + h * HD_;
  union { uint4 v; u16 s[8]; } a0, a1;
  a0.v = *(const uint4*)&QKV[row + g * 8];
  a1.v = *(const uint4*)&QKV[row + 32 + g * 8];
#pragma unroll
  for (int e = 0; e < 8; ++e) L[(g * 8 + e) * 72 + r] = a0.s[e];
#pragma unroll
  for (int e = 0; e < 8; ++e) L[(32 + g * 8 + e) * 72 + r] = a1.s[e];
  __syncthreads();
  size_t orow = ((size_t)(bh * 64 + r)) * T_ + tt * 64;
  *(uint4*)&VT[orow + g * 8]      = *(uint4*)&L[r * 72 + g * 8];
  *(uint4*)&VT[orow + 32 + g * 8] = *(uint4*)&L[r * 72 + 32 + g * 8];
}

// ------- Flash attention (causal): wave-autonomous 64q tiles --------------
// Wave = (bh, qt, z) unit: 64 queries (4 j-strips of 16), k-tiles kb ≡ z
// (mod 3), kb <= qt. No barriers, no intra-block sharing. 768 blocks (3/CU).
// Partials: O_z = A_z/l_z (bf16) + l_z; combined by ared_kernel.
__global__ __launch_bounds__(256, 3) void attn_kernel(const u16* __restrict__ QKV,
    const u16* __restrict__ VT, u16* __restrict__ Opart, float* __restrict__ lpart) {
  int bh = blockIdx.x, g = blockIdx.y, z = blockIdx.z;
  int b = bh >> 4, h = bh & 15;
  int tid = threadIdx.x, lane = tid & 63, wid = tid >> 6;
  int quad = lane >> 4, lcol = lane & 15;
  __shared__ __align__(16) u16 Ps[4][4 * 16 * 72];   // per-wave, per-j P[q16][kt64]
  const float SC = 0.125f * 1.44269504f;             // hd^-0.5 * log2(e)
  const float EB = 8.0f * 1.44269504f;               // fixed exp base (score 8.0)
  int qt = wid * 8 + g;                              // this wave's 64q tile
  const u16* kbase = QKV + (size_t)b * T_ * QKVC + C_ + h * HD_;
  const u16* vbase = VT + (size_t)(bh * 64) * T_;
  u16* psw = Ps[wid];
  u16* Os = Opart + (size_t)z * NT * C_;
  float* ls = lpart + (size_t)z * 32 * T_;

  int qg[4];
  v8s bq[4][2];
#pragma unroll
  for (int j = 0; j < 4; ++j) {
    qg[j] = qt * 64 + j * 16 + lcol;
#pragma unroll
    for (int kh = 0; kh < 2; ++kh)
      bq[j][kh] = *(const v8s*)&QKV[(size_t)(b * T_ + qg[j]) * QKVC + h * HD_ + kh * 32 + quad * 8];
  }
  float l_i[4] = {0.f, 0.f, 0.f, 0.f};
  v4f accO[4][4] = {};   // [df][j]

  for (int kb = z; kb <= qt; kb += 3) {
    bool diag = (kb == qt);
    // ---- QK + softmax phase (ak live) ----
    {
      v8s ak[4][2];
#pragma unroll
      for (int cg = 0; cg < 4; ++cg)
#pragma unroll
        for (int kh = 0; kh < 2; ++kh)
          ak[cg][kh] = *(const v8s*)&kbase[(size_t)(kb * 64 + cg * 16 + lcol) * QKVC + kh * 32 + quad * 8];
#pragma unroll
      for (int j = 0; j < 4; ++j) {
        v4f s[4];
#pragma unroll
        for (int cg = 0; cg < 4; ++cg) {
          v4f acc = {};
          acc = mfma16(ak[cg][1], bq[j][1], acc);
          s[cg] = mfma16(ak[cg][0], bq[j][0], acc);
        }
        float ps = 0.f;
#pragma unroll
        for (int cg = 0; cg < 4; ++cg) {
          union { u16 s4[4]; unsigned long long ll; } pk;
#pragma unroll
          for (int rg = 0; rg < 4; ++rg) {
            float pv = exp2f(s[cg][rg] * SC - EB);
            if (diag) {
              int kt = kb * 64 + cg * 16 + quad * 4 + rg;
              pv = (kt <= qg[j]) ? pv : 0.f;
            }
            ps += pv;
            pk.s4[rg] = f2bt(pv);
          }
          *(unsigned long long*)&psw[j * 1152 + lcol * 72 + cg * 16 + quad * 4] = pk.ll;
        }
        ps += __shfl_xor(ps, 16);
        ps += __shfl_xor(ps, 32);
        l_i[j] += ps;
      }
    }
    // ---- PV phase (av live, ak dead) ----
    v8s av[4][2];
#pragma unroll
    for (int df = 0; df < 4; ++df)
#pragma unroll
      for (int kh = 0; kh < 2; ++kh)
        av[df][kh] = *(const v8s*)&vbase[(size_t)(df * 16 + lcol) * T_ + kb * 64 + kh * 32 + quad * 8];
#pragma unroll
    for (int j = 0; j < 4; ++j) {
      v8s bp0 = *(v8s*)&psw[j * 1152 + lcol * 72 + quad * 8];
      v8s bp1 = *(v8s*)&psw[j * 1152 + lcol * 72 + 32 + quad * 8];
#pragma unroll
      for (int df = 0; df < 4; ++df) {
        v4f t = mfma16(av[df][1], bp1, accO[df][j]);
        accO[df][j] = mfma16(av[df][0], bp0, t);
      }
    }
  }
#pragma unroll
  for (int j = 0; j < 4; ++j) {
    float inv = (l_i[j] > 0.f) ? (1.f / l_i[j]) : 0.f;
    size_t orow = ((size_t)(b * T_ + qg[j])) * C_ + h * HD_;
    if (quad == 0) ls[bh * T_ + qg[j]] = l_i[j];
#pragma unroll
    for (int df = 0; df < 4; ++df) {
      union { u16 s4[4]; unsigned long long ll; } ok;
#pragma unroll
      for (int rg = 0; rg < 4; ++rg) ok.s4[rg] = f2b(accO[df][j][rg] * inv);
      *(unsigned long long*)&Os[orow + df * 16 + quad * 4] = ok.ll;
    }
  }
}

// ------- attention split combine: Ob = sum_z(Oz*lz) / sum_z(lz) -----------
// Ob aliases partial z0: each thread reads all partials before writing.
__global__ __launch_bounds__(256) void ared_kernel(const u16* __restrict__ Opart,
    const float* __restrict__ lpart, u16* __restrict__ Ob) {
  size_t e0 = ((size_t)blockIdx.x * 256 + threadIdx.x) * 4;
  int tb = (int)(e0 >> 10);                 // b*T + t
  int col = (int)(e0 & (C_ - 1));
  int bq = tb >> 11, t = tb & (T_ - 1);
  int h = col >> 6;
  int lidx = (bq * 16 + h) * T_ + t;
  float l0 = lpart[lidx];
  float l1 = lpart[32 * T_ + lidx];
  float l2 = lpart[64 * T_ + lidx];
  float inv = 1.f / (l0 + l1 + l2);
  float w0 = l0 * inv, w1 = l1 * inv, w2 = l2 * inv;
  union { uint2 v; u16 s[4]; } a, b, c, o;
  a.v = *(const uint2*)&Opart[e0];
  b.v = *(const uint2*)&Opart[(size_t)NT * C_ + e0];
  c.v = *(const uint2*)&Opart[(size_t)2 * NT * C_ + e0];
#pragma unroll
  for (int i = 0; i < 4; ++i)
    o.s[i] = f2b(b2f(a.s[i]) * w0 + b2f(b.s[i]) * w1 + b2f(c.s[i]) * w2);
  *(uint2*)&Ob[e0] = o.v;
}

extern "C" void kernel_launch(void* const* d_in, const int* in_sizes, int n_in,
                              void* d_out, int out_size, void* d_ws, size_t ws_size,
                              hipStream_t stream) {
  (void)in_sizes; (void)n_in; (void)out_size; (void)ws_size;
  const float* x    = (const float*)d_in[0];
  const float* ln1w = (const float*)d_in[1];
  const float* ln1b = (const float*)d_in[2];
  const float* Wq   = (const float*)d_in[3];
  const float* Wk   = (const float*)d_in[4];
  const float* Wv   = (const float*)d_in[5];
  const float* Wp   = (const float*)d_in[6];
  const float* bp   = (const float*)d_in[7];
  const float* ln2w = (const float*)d_in[8];
  const float* ln2b = (const float*)d_in[9];
  const float* W1   = (const float*)d_in[10];
  const float* b1   = (const float*)d_in[11];
  const float* W2   = (const float*)d_in[12];
  const float* b2   = (const float*)d_in[13];
  float* out = (float*)d_out;
  char* ws = (char*)d_ws;
  const size_t MB = 1024 * 1024;
  u16*   h1    = (u16*)(ws);             // 0..8 MB
  u16*   VT    = (u16*)(ws);             // 0..8 MB, overlays h1
  u16*   QKVb  = (u16*)(ws + 8  * MB);   // 8..32 MB [4096,3072] bf16
  u16*   Ob    = (u16*)(ws + 32 * MB);   // 32..40 MB (aliases attn partial z0)
  u16*   Opart = (u16*)(ws + 32 * MB);   // 32..56 MB: 3x bf16 [4096,1024] partials
  float* xa    = (float*)(ws + 40 * MB); // 40..56 MB fp32 (after ared)
  u16*   h2    = (u16*)(ws);             // overlays VT (dead after attn)
  u16*   f1    = (u16*)(ws + 8 * MB);    // 8..40 MB, overlays QKVb+Ob (dead)
  u16*   Wqkvt = (u16*)(ws + 56 * MB);   // 56..62 MB [3072,1024] bf16
  float* lpart = (float*)(ws + 56 * MB); // 56..56.8 MB, overlays dead Wqkvt
  u16*   Wpt   = (u16*)(ws + 62 * MB);   // 62..64 MB [1024,1024]
  u16*   W1t   = (u16*)(ws + 64 * MB);   // 64..72 MB [4096,1024]
  u16*   W2t   = (u16*)(ws + 72 * MB);   // 72..80 MB [1024,4096]
  float* p0    = (float*)(ws + 56 * MB); // 56..72 MB fp32 partial (W2 stage)

  wcvt_kernel<<<dim3(32, 32),  256, 0, stream>>>(Wq, Wqkvt,                1024, 1024);
  wcvt_kernel<<<dim3(32, 32),  256, 0, stream>>>(Wk, Wqkvt + 1024 * 1024,  1024, 1024);
  wcvt_kernel<<<dim3(32, 32),  256, 0, stream>>>(Wv, Wqkvt + 2048 * 1024,  1024, 1024);
  wcvt_kernel<<<dim3(32, 32),  256, 0, stream>>>(Wp, Wpt,                  1024, 1024);
  wcvt_kernel<<<dim3(128, 32), 256, 0, stream>>>(W1, W1t,                  1024, 4096);
  wcvt_kernel<<<dim3(32, 128), 256, 0, stream>>>(W2, W2t,                  4096, 1024);

  ln_kernel<<<NT, 256, 0, stream>>>(x, ln1w, ln1b, h1);
  gemm_bt<<<dim3(QKVC / 128, NT / 128, 1), 256, 0, stream>>>(
      h1, Wqkvt, nullptr, nullptr, QKVb, nullptr, nullptr, NT, QKVC, C_, C_, C_, 0);
  vt_kernel<<<dim3(B_ * NH_, T_ / 64), 256, 0, stream>>>(QKVb, VT);
  attn_kernel<<<dim3(B_ * NH_, 8, 3), 256, 0, stream>>>(QKVb, VT, Opart, lpart);
  ared_kernel<<<(NT * C_) / (256 * 4), 256, 0, stream>>>(Opart, lpart, Ob);
  gemm_bt_n64<<<dim3(C_ / 64, NT / 128), 256, 0, stream>>>(
      Ob, Wpt, bp, x, nullptr, xa, NT, C_, C_, 0);
  ln_kernel<<<NT, 256, 0, stream>>>(xa, ln2w, ln2b, h2);
  gemm_bt<<<dim3(FF_ / 128, NT / 128, 1), 256, 0, stream>>>(
      h2, W1t, b1, nullptr, f1, nullptr, nullptr, NT, FF_, C_, C_, C_, 1);
  // W2 split-K=2: z=0 -> p0, z=1 -> out; then out = out + p0 + b2 + xa
  gemm_bt<<<dim3(C_ / 128, NT / 128, 2), 256, 0, stream>>>(
      f1, W2t, nullptr, nullptr, nullptr, p0, out, NT, C_, FF_, FF_, FF_ / 2, 0);
  add4_kernel<<<(NT * C_) / (256 * 4), 256, 0, stream>>>(out, p0, b2, xa);
}

// Round 12
// 391.821 us; speedup vs baseline: 1.2226x; 1.0980x over previous
//
#include <hip/hip_runtime.h>
#include <hip/hip_bf16.h>

using u16 = unsigned short;
typedef short v8s __attribute__((ext_vector_type(8)));
typedef float v4f __attribute__((ext_vector_type(4)));

#define B_ 2
#define T_ 2048
#define C_ 1024
#define NH_ 16
#define HD_ 64
#define FF_ 4096
#define NT (B_*T_)
#define QKVC 3072

__device__ __forceinline__ u16 f2b(float f) {
  union { float f; unsigned int i; } v; v.f = f;
  unsigned int r = (v.i + 0x7FFFu + ((v.i >> 16) & 1u)) >> 16;
  return (u16)r;
}
__device__ __forceinline__ u16 f2bt(float f) {   // truncating bf16 (1 op)
  union { float f; unsigned int i; } v; v.f = f;
  return (u16)(v.i >> 16);
}
__device__ __forceinline__ float b2f(u16 u) {
  union { unsigned int i; float f; } v; v.i = ((unsigned int)u) << 16; return v.f;
}
__device__ __forceinline__ v4f mfma16(v8s a, v8s b, v4f c) {
  return __builtin_amdgcn_mfma_f32_16x16x32_bf16(a, b, c, 0, 0, 0);
}
__device__ __forceinline__ void glds16(const u16* g, u16* l) {
  __builtin_amdgcn_global_load_lds(
      (const __attribute__((address_space(1))) unsigned int*)g,
      (__attribute__((address_space(3))) unsigned int*)l, 16, 0, 0);
}

// ------- all weight converts in ONE launch: W[K,N] fp32 -> Wt[N,K] bf16 ---
__global__ __launch_bounds__(256) void wcvt_all(
    const float* __restrict__ Wq, const float* __restrict__ Wk,
    const float* __restrict__ Wv, const float* __restrict__ Wp,
    const float* __restrict__ W1, const float* __restrict__ W2,
    u16* __restrict__ Wqkvt, u16* __restrict__ Wpt,
    u16* __restrict__ W1t, u16* __restrict__ W2t) {
  int id = blockIdx.x;
  const float* W; u16* Wt; int K, N, bx, by;
  if (id < 4096) {           // Wq, Wk, Wv, Wp: each 32x32 blocks
    int wsel = id >> 10, r = id & 1023;
    bx = r & 31; by = r >> 5; K = 1024; N = 1024;
    W  = wsel == 0 ? Wq : wsel == 1 ? Wk : wsel == 2 ? Wv : Wp;
    Wt = wsel == 3 ? Wpt : (Wqkvt + (size_t)wsel * 1024 * 1024);
  } else if (id < 8192) {    // W1: [1024,4096], 128x32 blocks
    int r = id - 4096;
    bx = r & 127; by = r >> 7; K = 1024; N = 4096; W = W1; Wt = W1t;
  } else {                   // W2: [4096,1024], 32x128 blocks
    int r = id - 8192;
    bx = r & 31; by = r >> 5; K = 4096; N = 1024; W = W2; Wt = W2t;
  }
  __shared__ float t[32][33];
  int tx = threadIdx.x & 31, ty = threadIdx.x >> 5;
  int n0 = bx * 32, k0 = by * 32;
#pragma unroll
  for (int j = 0; j < 4; ++j)
    t[ty + j * 8][tx] = W[(size_t)(k0 + ty + j * 8) * N + n0 + tx];
  __syncthreads();
#pragma unroll
  for (int j = 0; j < 4; ++j)
    Wt[(size_t)(n0 + ty + j * 8) * K + k0 + tx] = f2b(t[tx][ty + j * 8]);
}

// ------- LayerNorm: fp32 in -> bf16 out, one block per row (C=1024) -------
__global__ __launch_bounds__(256) void ln_kernel(const float* __restrict__ x,
    const float* __restrict__ w, const float* __restrict__ b, u16* __restrict__ y) {
  int row = blockIdx.x;
  int tid = threadIdx.x;
  const float* xr = x + (size_t)row * C_;
  float4 f4 = *(const float4*)&xr[tid * 4];
  float f[4] = {f4.x, f4.y, f4.z, f4.w};
  float s1 = 0.f, s2 = 0.f;
#pragma unroll
  for (int i = 0; i < 4; ++i) { s1 += f[i]; s2 += f[i] * f[i]; }
#pragma unroll
  for (int off = 32; off > 0; off >>= 1) {
    s1 += __shfl_down(s1, off);
    s2 += __shfl_down(s2, off);
  }
  __shared__ float red[10];
  int lane = tid & 63, wid = tid >> 6;
  if (lane == 0) { red[wid] = s1; red[4 + wid] = s2; }
  __syncthreads();
  if (tid == 0) {
    float a = red[0] + red[1] + red[2] + red[3];
    float q = red[4] + red[5] + red[6] + red[7];
    float mu = a * (1.f / C_);
    float var = q * (1.f / C_) - mu * mu;
    red[8] = mu; red[9] = rsqrtf(var + 1e-5f);
  }
  __syncthreads();
  float mu = red[8], rs = red[9];
  union { uint2 v; u16 s[4]; } st;
#pragma unroll
  for (int i = 0; i < 4; ++i) {
    int c = tid * 4 + i;
    st.s[i] = f2b((f[i] - mu) * rs * w[c] + b[c]);
  }
  *(uint2*)&y[(size_t)row * C_ + tid * 4] = st.v;
}

// ------- GEMM: Y[M,N] = X[M,K] @ Wt[N,K]^T, 128x128 tile, BK=64 ----------
// MFMA operands swapped (C^T frags): lanes = m, regs = 4 consecutive n ->
// epilogue uses packed 8B (bf16) / float4 (fp32) stores + float4 bias/res.
__global__ __launch_bounds__(256) void gemm_bt(const u16* __restrict__ X,
    const u16* __restrict__ Wt, const float* __restrict__ bias,
    const float* __restrict__ resf, u16* __restrict__ Yb, float* __restrict__ Yf,
    float* __restrict__ Yfz1, int M, int N, int lda, int ldb, int kspl, int relu) {
  __shared__ __align__(16) u16 As[2][128 * 32];
  __shared__ __align__(16) u16 Bs[2][128 * 32];
  int tid = threadIdx.x, lane = tid & 63, w = tid >> 6;
  int wm = w >> 1, wn = w & 1, quad = lane >> 4, lcol = lane & 15;
  int m0 = blockIdx.y * 128, n0 = blockIdx.x * 128;
  int koff = blockIdx.z * kspl;
  v4f acc[4][4] = {};   // [i=m-frag][j=n-frag], regs = n (C^T)
  int sr = lane >> 2, sc = lane & 3;
  const u16* gA = X  + (size_t)(m0 + w * 32 + sr) * lda + koff + sc * 8;
  const u16* gB = Wt + (size_t)(n0 + w * 32 + sr) * ldb + koff + sc * 8;
  u16* lA0 = As[0] + (w * 32) * 32;
  u16* lA1 = As[1] + (w * 32) * 32;
  u16* lB0 = Bs[0] + (w * 32) * 32;
  u16* lB1 = Bs[1] + (w * 32) * 32;
  for (int k0 = 0; k0 < kspl; k0 += 64) {
    __syncthreads();
    glds16(gA + k0,                        lA0);
    glds16(gA + k0 + (size_t)16 * lda,     lA0 + 16 * 32);
    glds16(gA + k0 + 32,                   lA1);
    glds16(gA + k0 + 32 + (size_t)16 * lda, lA1 + 16 * 32);
    glds16(gB + k0,                        lB0);
    glds16(gB + k0 + (size_t)16 * ldb,     lB0 + 16 * 32);
    glds16(gB + k0 + 32,                   lB1);
    glds16(gB + k0 + 32 + (size_t)16 * ldb, lB1 + 16 * 32);
    __syncthreads();
#pragma unroll
    for (int kh = 0; kh < 2; ++kh) {
      v8s a[4], b[4];
#pragma unroll
      for (int i = 0; i < 4; ++i) {
        a[i] = *(v8s*)&As[kh][(wm * 64 + i * 16 + lcol) * 32 + quad * 8];
        b[i] = *(v8s*)&Bs[kh][(wn * 64 + i * 16 + lcol) * 32 + quad * 8];
      }
#pragma unroll
      for (int i = 0; i < 4; ++i)
#pragma unroll
        for (int j = 0; j < 4; ++j)
          acc[i][j] = mfma16(b[j], a[i], acc[i][j]);   // C^T fragments
    }
  }
  float* yf = blockIdx.z ? Yfz1 : Yf;
#pragma unroll
  for (int i = 0; i < 4; ++i) {
    int m = m0 + wm * 64 + i * 16 + lcol;
#pragma unroll
    for (int j = 0; j < 4; ++j) {
      int n = n0 + wn * 64 + j * 16 + quad * 4;
      v4f v = acc[i][j];
      if (bias) {
        float4 bb = *(const float4*)&bias[n];
        v[0] += bb.x; v[1] += bb.y; v[2] += bb.z; v[3] += bb.w;
      }
      if (resf) {
        float4 rr = *(const float4*)&resf[(size_t)m * N + n];
        v[0] += rr.x; v[1] += rr.y; v[2] += rr.z; v[3] += rr.w;
      }
      if (relu) {
#pragma unroll
        for (int r = 0; r < 4; ++r) v[r] = fmaxf(v[r], 0.f);
      }
      if (Yb) {
        union { u16 s4[4]; unsigned long long ll; } pk;
#pragma unroll
        for (int r = 0; r < 4; ++r) pk.s4[r] = f2b(v[r]);
        *(unsigned long long*)&Yb[(size_t)m * N + n] = pk.ll;
      } else {
        *(v4f*)&yf[(size_t)m * N + n] = v;
      }
    }
  }
}

// ------- GEMM variant for small N: 128x64 tile, BK=64, C^T epilogue ------
__global__ __launch_bounds__(256) void gemm_bt_n64(const u16* __restrict__ X,
    const u16* __restrict__ Wt, const float* __restrict__ bias,
    const float* __restrict__ resf, u16* __restrict__ Yb, float* __restrict__ Yf,
    int M, int N, int K, int relu) {
  __shared__ __align__(16) u16 As[2][128 * 32];
  __shared__ __align__(16) u16 Bs[2][64 * 32];
  int tid = threadIdx.x, lane = tid & 63, w = tid >> 6;
  int wm = w >> 1, wn = w & 1, quad = lane >> 4, lcol = lane & 15;
  int m0 = blockIdx.y * 128, n0 = blockIdx.x * 64;
  v4f acc[4][2] = {};
  int sr = lane >> 2, sc = lane & 3;
  const u16* gA = X  + (size_t)(m0 + w * 32 + sr) * K + sc * 8;
  const u16* gB = Wt + (size_t)(n0 + w * 16 + sr) * K + sc * 8;
  u16* lA0 = As[0] + (w * 32) * 32;
  u16* lA1 = As[1] + (w * 32) * 32;
  u16* lB0 = Bs[0] + (w * 16) * 32;
  u16* lB1 = Bs[1] + (w * 16) * 32;
  for (int k0 = 0; k0 < K; k0 += 64) {
    __syncthreads();
    glds16(gA + k0,                       lA0);
    glds16(gA + k0 + (size_t)16 * K,      lA0 + 16 * 32);
    glds16(gA + k0 + 32,                  lA1);
    glds16(gA + k0 + 32 + (size_t)16 * K, lA1 + 16 * 32);
    glds16(gB + k0,                       lB0);
    glds16(gB + k0 + 32,                  lB1);
    __syncthreads();
#pragma unroll
    for (int kh = 0; kh < 2; ++kh) {
      v8s a[4], b[2];
#pragma unroll
      for (int i = 0; i < 4; ++i)
        a[i] = *(v8s*)&As[kh][(wm * 64 + i * 16 + lcol) * 32 + quad * 8];
#pragma unroll
      for (int j = 0; j < 2; ++j)
        b[j] = *(v8s*)&Bs[kh][(wn * 32 + j * 16 + lcol) * 32 + quad * 8];
#pragma unroll
      for (int i = 0; i < 4; ++i)
#pragma unroll
        for (int j = 0; j < 2; ++j)
          acc[i][j] = mfma16(b[j], a[i], acc[i][j]);   // C^T fragments
    }
  }
#pragma unroll
  for (int i = 0; i < 4; ++i) {
    int m = m0 + wm * 64 + i * 16 + lcol;
#pragma unroll
    for (int j = 0; j < 2; ++j) {
      int n = n0 + wn * 32 + j * 16 + quad * 4;
      v4f v = acc[i][j];
      if (bias) {
        float4 bb = *(const float4*)&bias[n];
        v[0] += bb.x; v[1] += bb.y; v[2] += bb.z; v[3] += bb.w;
      }
      if (resf) {
        float4 rr = *(const float4*)&resf[(size_t)m * N + n];
        v[0] += rr.x; v[1] += rr.y; v[2] += rr.z; v[3] += rr.w;
      }
      if (relu) {
#pragma unroll
        for (int r = 0; r < 4; ++r) v[r] = fmaxf(v[r], 0.f);
      }
      if (Yb) {
        union { u16 s4[4]; unsigned long long ll; } pk;
#pragma unroll
        for (int r = 0; r < 4; ++r) pk.s4[r] = f2b(v[r]);
        *(unsigned long long*)&Yb[(size_t)m * N + n] = pk.ll;
      } else {
        *(v4f*)&Yf[(size_t)m * N + n] = v;
      }
    }
  }
}

// ------- split-K reduce: out = out(p1) + p0 + bias + res ------------------
__global__ __launch_bounds__(256) void add4_kernel(float* __restrict__ out,
    const float* __restrict__ p0, const float* __restrict__ bias,
    const float* __restrict__ res) {
  size_t e0 = ((size_t)blockIdx.x * 256 + threadIdx.x) * 4;
  int col = (int)(e0 & (C_ - 1));
  float4 o = *(float4*)&out[e0];
  float4 p = *(const float4*)&p0[e0];
  float4 r = *(const float4*)&res[e0];
  float4 bb = *(const float4*)&bias[col];
  o.x += p.x + r.x + bb.x;
  o.y += p.y + r.y + bb.y;
  o.z += p.z + r.z + bb.z;
  o.w += p.w + r.w + bb.w;
  *(float4*)&out[e0] = o;
}

// ------- V transpose: QKV v-columns -> VT[bh][d][t] bf16 ------------------
__global__ __launch_bounds__(256) void vt_kernel(const u16* __restrict__ QKV,
    u16* __restrict__ VT) {
  int bh = blockIdx.x, tt = blockIdx.y;
  int b = bh >> 4, h = bh & 15;
  int tid = threadIdx.x;
  __shared__ u16 L[64 * 72];  // L[d][t]
  int r = tid >> 2, g = tid & 3;
  size_t row = ((size_t)(b * T_ + tt * 64 + r)) * QKVC + 2 * C_ + h * HD_;
  union { uint4 v; u16 s[8]; } a0, a1;
  a0.v = *(const uint4*)&QKV[row + g * 8];
  a1.v = *(const uint4*)&QKV[row + 32 + g * 8];
#pragma unroll
  for (int e = 0; e < 8; ++e) L[(g * 8 + e) * 72 + r] = a0.s[e];
#pragma unroll
  for (int e = 0; e < 8; ++e) L[(32 + g * 8 + e) * 72 + r] = a1.s[e];
  __syncthreads();
  size_t orow = ((size_t)(bh * 64 + r)) * T_ + tt * 64;
  *(uint4*)&VT[orow + g * 8]      = *(uint4*)&L[r * 72 + g * 8];
  *(uint4*)&VT[orow + 32 + g * 8] = *(uint4*)&L[r * 72 + 32 + g * 8];
}

// ------- Flash attention (causal): wave-autonomous 64q tiles --------------
__global__ __launch_bounds__(256, 3) void attn_kernel(const u16* __restrict__ QKV,
    const u16* __restrict__ VT, u16* __restrict__ Opart, float* __restrict__ lpart) {
  int bh = blockIdx.x, g = blockIdx.y, z = blockIdx.z;
  int b = bh >> 4, h = bh & 15;
  int tid = threadIdx.x, lane = tid & 63, wid = tid >> 6;
  int quad = lane >> 4, lcol = lane & 15;
  __shared__ __align__(16) u16 Ps[4][4 * 16 * 72];   // per-wave, per-j P[q16][kt64]
  const float SC = 0.125f * 1.44269504f;             // hd^-0.5 * log2(e)
  const float EB = 8.0f * 1.44269504f;               // fixed exp base (score 8.0)
  int qt = wid * 8 + g;                              // this wave's 64q tile
  const u16* kbase = QKV + (size_t)b * T_ * QKVC + C_ + h * HD_;
  const u16* vbase = VT + (size_t)(bh * 64) * T_;
  u16* psw = Ps[wid];
  u16* Os = Opart + (size_t)z * NT * C_;
  float* ls = lpart + (size_t)z * 32 * T_;

  int qg[4];
  v8s bq[4][2];
#pragma unroll
  for (int j = 0; j < 4; ++j) {
    qg[j] = qt * 64 + j * 16 + lcol;
#pragma unroll
    for (int kh = 0; kh < 2; ++kh)
      bq[j][kh] = *(const v8s*)&QKV[(size_t)(b * T_ + qg[j]) * QKVC + h * HD_ + kh * 32 + quad * 8];
  }
  float l_i[4] = {0.f, 0.f, 0.f, 0.f};
  v4f accO[4][4] = {};   // [df][j]

  for (int kb = z; kb <= qt; kb += 3) {
    bool diag = (kb == qt);
    {
      v8s ak[4][2];
#pragma unroll
      for (int cg = 0; cg < 4; ++cg)
#pragma unroll
        for (int kh = 0; kh < 2; ++kh)
          ak[cg][kh] = *(const v8s*)&kbase[(size_t)(kb * 64 + cg * 16 + lcol) * QKVC + kh * 32 + quad * 8];
#pragma unroll
      for (int j = 0; j < 4; ++j) {
        v4f s[4];
#pragma unroll
        for (int cg = 0; cg < 4; ++cg) {
          v4f acc = {};
          acc = mfma16(ak[cg][1], bq[j][1], acc);
          s[cg] = mfma16(ak[cg][0], bq[j][0], acc);
        }
        float ps = 0.f;
#pragma unroll
        for (int cg = 0; cg < 4; ++cg) {
          union { u16 s4[4]; unsigned long long ll; } pk;
#pragma unroll
          for (int rg = 0; rg < 4; ++rg) {
            float pv = exp2f(s[cg][rg] * SC - EB);
            if (diag) {
              int kt = kb * 64 + cg * 16 + quad * 4 + rg;
              pv = (kt <= qg[j]) ? pv : 0.f;
            }
            ps += pv;
            pk.s4[rg] = f2bt(pv);
          }
          *(unsigned long long*)&psw[j * 1152 + lcol * 72 + cg * 16 + quad * 4] = pk.ll;
        }
        ps += __shfl_xor(ps, 16);
        ps += __shfl_xor(ps, 32);
        l_i[j] += ps;
      }
    }
    v8s av[4][2];
#pragma unroll
    for (int df = 0; df < 4; ++df)
#pragma unroll
      for (int kh = 0; kh < 2; ++kh)
        av[df][kh] = *(const v8s*)&vbase[(size_t)(df * 16 + lcol) * T_ + kb * 64 + kh * 32 + quad * 8];
#pragma unroll
    for (int j = 0; j < 4; ++j) {
      v8s bp0 = *(v8s*)&psw[j * 1152 + lcol * 72 + quad * 8];
      v8s bp1 = *(v8s*)&psw[j * 1152 + lcol * 72 + 32 + quad * 8];
#pragma unroll
      for (int df = 0; df < 4; ++df) {
        v4f t = mfma16(av[df][1], bp1, accO[df][j]);
        accO[df][j] = mfma16(av[df][0], bp0, t);
      }
    }
  }
#pragma unroll
  for (int j = 0; j < 4; ++j) {
    float inv = (l_i[j] > 0.f) ? (1.f / l_i[j]) : 0.f;
    size_t orow = ((size_t)(b * T_ + qg[j])) * C_ + h * HD_;
    if (quad == 0) ls[bh * T_ + qg[j]] = l_i[j];
#pragma unroll
    for (int df = 0; df < 4; ++df) {
      union { u16 s4[4]; unsigned long long ll; } ok;
#pragma unroll
      for (int rg = 0; rg < 4; ++rg) ok.s4[rg] = f2b(accO[df][j][rg] * inv);
      *(unsigned long long*)&Os[orow + df * 16 + quad * 4] = ok.ll;
    }
  }
}

// ------- attention split combine: Ob = sum_z(Oz*lz) / sum_z(lz) -----------
__global__ __launch_bounds__(256) void ared_kernel(const u16* __restrict__ Opart,
    const float* __restrict__ lpart, u16* __restrict__ Ob) {
  size_t e0 = ((size_t)blockIdx.x * 256 + threadIdx.x) * 4;
  int tb = (int)(e0 >> 10);                 // b*T + t
  int col = (int)(e0 & (C_ - 1));
  int bq = tb >> 11, t = tb & (T_ - 1);
  int h = col >> 6;
  int lidx = (bq * 16 + h) * T_ + t;
  float l0 = lpart[lidx];
  float l1 = lpart[32 * T_ + lidx];
  float l2 = lpart[64 * T_ + lidx];
  float inv = 1.f / (l0 + l1 + l2);
  float w0 = l0 * inv, w1 = l1 * inv, w2 = l2 * inv;
  union { uint2 v; u16 s[4]; } a, b, c, o;
  a.v = *(const uint2*)&Opart[e0];
  b.v = *(const uint2*)&Opart[(size_t)NT * C_ + e0];
  c.v = *(const uint2*)&Opart[(size_t)2 * NT * C_ + e0];
#pragma unroll
  for (int i = 0; i < 4; ++i)
    o.s[i] = f2b(b2f(a.s[i]) * w0 + b2f(b.s[i]) * w1 + b2f(c.s[i]) * w2);
  *(uint2*)&Ob[e0] = o.v;
}

extern "C" void kernel_launch(void* const* d_in, const int* in_sizes, int n_in,
                              void* d_out, int out_size, void* d_ws, size_t ws_size,
                              hipStream_t stream) {
  (void)in_sizes; (void)n_in; (void)out_size; (void)ws_size;
  const float* x    = (const float*)d_in[0];
  const float* ln1w = (const float*)d_in[1];
  const float* ln1b = (const float*)d_in[2];
  const float* Wq   = (const float*)d_in[3];
  const float* Wk   = (const float*)d_in[4];
  const float* Wv   = (const float*)d_in[5];
  const float* Wp   = (const float*)d_in[6];
  const float* bp   = (const float*)d_in[7];
  const float* ln2w = (const float*)d_in[8];
  const float* ln2b = (const float*)d_in[9];
  const float* W1   = (const float*)d_in[10];
  const float* b1   = (const float*)d_in[11];
  const float* W2   = (const float*)d_in[12];
  const float* b2   = (const float*)d_in[13];
  float* out = (float*)d_out;
  char* ws = (char*)d_ws;
  const size_t MB = 1024 * 1024;
  u16*   h1    = (u16*)(ws);             // 0..8 MB
  u16*   VT    = (u16*)(ws);             // 0..8 MB, overlays h1
  u16*   QKVb  = (u16*)(ws + 8  * MB);   // 8..32 MB [4096,3072] bf16
  u16*   Ob    = (u16*)(ws + 32 * MB);   // 32..40 MB (aliases attn partial z0)
  u16*   Opart = (u16*)(ws + 32 * MB);   // 32..56 MB: 3x bf16 [4096,1024] partials
  float* xa    = (float*)(ws + 40 * MB); // 40..56 MB fp32 (after ared)
  u16*   h2    = (u16*)(ws);             // overlays VT (dead after attn)
  u16*   f1    = (u16*)(ws + 8 * MB);    // 8..40 MB, overlays QKVb+Ob (dead)
  u16*   Wqkvt = (u16*)(ws + 56 * MB);   // 56..62 MB [3072,1024] bf16
  float* lpart = (float*)(ws + 56 * MB); // 56..56.8 MB, overlays dead Wqkvt
  u16*   Wpt   = (u16*)(ws + 62 * MB);   // 62..64 MB [1024,1024]
  u16*   W1t   = (u16*)(ws + 64 * MB);   // 64..72 MB [4096,1024]
  u16*   W2t   = (u16*)(ws + 72 * MB);   // 72..80 MB [1024,4096]
  float* p0    = (float*)(ws + 56 * MB); // 56..72 MB fp32 partial (W2 stage)

  wcvt_all<<<12288, 256, 0, stream>>>(Wq, Wk, Wv, Wp, W1, W2,
                                      Wqkvt, Wpt, W1t, W2t);
  ln_kernel<<<NT, 256, 0, stream>>>(x, ln1w, ln1b, h1);
  gemm_bt<<<dim3(QKVC / 128, NT / 128, 1), 256, 0, stream>>>(
      h1, Wqkvt, nullptr, nullptr, QKVb, nullptr, nullptr, NT, QKVC, C_, C_, C_, 0);
  vt_kernel<<<dim3(B_ * NH_, T_ / 64), 256, 0, stream>>>(QKVb, VT);
  attn_kernel<<<dim3(B_ * NH_, 8, 3), 256, 0, stream>>>(QKVb, VT, Opart, lpart);
  ared_kernel<<<(NT * C_) / (256 * 4), 256, 0, stream>>>(Opart, lpart, Ob);
  gemm_bt_n64<<<dim3(C_ / 64, NT / 128), 256, 0, stream>>>(
      Ob, Wpt, bp, x, nullptr, xa, NT, C_, C_, 0);
  ln_kernel<<<NT, 256, 0, stream>>>(xa, ln2w, ln2b, h2);
  gemm_bt<<<dim3(FF_ / 128, NT / 128, 1), 256, 0, stream>>>(
      h2, W1t, b1, nullptr, f1, nullptr, nullptr, NT, FF_, C_, C_, C_, 1);
  // W2 split-K=2: z=0 -> p0, z=1 -> out; then out = out + p0 + b2 + xa
  gemm_bt<<<dim3(C_ / 128, NT / 128, 2), 256, 0, stream>>>(
      f1, W2t, nullptr, nullptr, nullptr, p0, out, NT, C_, FF_, FF_, FF_ / 2, 0);
  add4_kernel<<<(NT * C_) / (256 * 4), 256, 0, stream>>>(out, p0, b2, xa);
}